// Round 9
// baseline (340.835 us; speedup 1.0000x reference)
//
#include <hip/hip_runtime.h>
#include <cmath>

constexpr int Bn = 64;    // batch
constexpr int Tn = 128;   // tgt len
constexpr int Sn = 1024;  // src len
constexpr int Dn = 1024;  // model dim

typedef __attribute__((ext_vector_type(8))) _Float16 half8;
typedef __attribute__((ext_vector_type(4))) _Float16 half4;
typedef __attribute__((ext_vector_type(4))) float float4v;

__device__ __forceinline__ void split2(float x, _Float16& h, _Float16& l) {
  h = (_Float16)x;
  l = (_Float16)(x - (float)h);
}

// ---------------------------------------------------------------------------
// LDS staging (ds_writes only; ordered by __syncthreads).
// [rows][BK] k-contiguous; row stride 40 halves (80 B) — 8-row bank period.
// ---------------------------------------------------------------------------

// 128-row f32 source -> split hi/lo, BK=32.
__device__ __forceinline__ void stageT_split(const float* __restrict__ G, size_t ld,
                                             int row0, int k0,
                                             _Float16 (*Sh)[40], _Float16 (*Sl)[40],
                                             int tid) {
#pragma unroll
  for (int it = 0; it < 4; ++it) {
    const int f = tid + it * 256;
    const int r = f >> 3, kq = (f & 7) << 2;
    const float4 v = *reinterpret_cast<const float4*>(G + (size_t)(row0 + r) * ld + k0 + kq);
    _Float16 h0, h1, h2, h3, l0, l1, l2, l3;
    split2(v.x, h0, l0); split2(v.y, h1, l1); split2(v.z, h2, l2); split2(v.w, h3, l3);
    half4 hv = {h0, h1, h2, h3};
    half4 lv = {l0, l1, l2, l3};
    *reinterpret_cast<half4*>(&Sh[r][kq]) = hv;
    *reinterpret_cast<half4*>(&Sl[r][kq]) = lv;
  }
}

// 128-row f32 source -> plain fp16, BK=32.
__device__ __forceinline__ void stageT_plain(const float* __restrict__ G, size_t ld,
                                             int row0, int k0,
                                             _Float16 (*Sh)[40], int tid) {
#pragma unroll
  for (int it = 0; it < 4; ++it) {
    const int f = tid + it * 256;
    const int r = f >> 3, kq = (f & 7) << 2;
    const float4 v = *reinterpret_cast<const float4*>(G + (size_t)(row0 + r) * ld + k0 + kq);
    half4 hv = {(_Float16)v.x, (_Float16)v.y, (_Float16)v.z, (_Float16)v.w};
    *reinterpret_cast<half4*>(&Sh[r][kq]) = hv;
  }
}

// Pre-split fp16 source (q) -> copy, 128 rows, BK=32.
__device__ __forceinline__ void stageT_h16(const _Float16* __restrict__ Gh,
                                           const _Float16* __restrict__ Gl, size_t ld,
                                           int row0, int k0,
                                           _Float16 (*Sh)[40], _Float16 (*Sl)[40],
                                           int tid) {
#pragma unroll
  for (int it = 0; it < 2; ++it) {
    const int f = tid + it * 256;
    const int r = f >> 2, kq = (f & 3) << 3;
    *reinterpret_cast<half8*>(&Sh[r][kq]) =
        *reinterpret_cast<const half8*>(Gh + (size_t)(row0 + r) * ld + k0 + kq);
    *reinterpret_cast<half8*>(&Sl[r][kq]) =
        *reinterpret_cast<const half8*>(Gl + (size_t)(row0 + r) * ld + k0 + kq);
  }
}

// fp16 source, 128 rows x 32 k: pure copy.
__device__ __forceinline__ void stage128x32_h16(const _Float16* __restrict__ G, size_t ld,
                                                int row0, int k0,
                                                _Float16 (*Sh)[40], int tid) {
#pragma unroll
  for (int it = 0; it < 2; ++it) {
    const int f = tid + it * 256;
    const int r = f >> 2, kq = (f & 3) << 3;
    *reinterpret_cast<half8*>(&Sh[r][kq]) =
        *reinterpret_cast<const half8*>(G + (size_t)(row0 + r) * ld + k0 + kq);
  }
}

// g4 B: mb tile [32 k][128 d] f32 -> WRITE-TRANSPOSED fp16 [128 d][44 k].
__device__ __forceinline__ void stageB_trans(const float* __restrict__ G, size_t ld,
                                             int k0, int col0,
                                             _Float16 (*Bt)[44], int tid) {
  const int d = tid & 127;
  const int kb = (tid >> 7) * 4;       // 0 or 4
#pragma unroll
  for (int it = 0; it < 4; ++it) {
    const int kq = kb + it * 8;        // covers 0..31
    _Float16 h[4];
#pragma unroll
    for (int j = 0; j < 4; ++j)
      h[j] = (_Float16)G[(size_t)(k0 + kq + j) * ld + col0 + d];
    half4 hv = {h[0], h[1], h[2], h[3]};
    *reinterpret_cast<half4*>(&Bt[d][kq]) = hv;
  }
}

// ---------------------------------------------------------------------------
// MFMA cores, 16x16x32. Input frag: row/col = lane&15, k = 8*(lane>>4)+[0..7].
// C/D: col = lane&15, row = (lane>>4)*4 + i  [m89-verified].
// 128x128 tile, 4 waves 2x2 (wr,wc in {0,1}).
// ---------------------------------------------------------------------------

// A split x B split (3 terms).
__device__ __forceinline__ void mma128_split3(const _Float16 (*Ah)[40], const _Float16 (*Al)[40],
                                              const _Float16 (*Bh)[40], const _Float16 (*Bl)[40],
                                              float4v acc[4][4], int lane, int wr, int wc) {
  const int g = lane >> 4, rr = lane & 15, kb = g << 3;
  half8 ah[4], al[4];
#pragma unroll
  for (int m = 0; m < 4; ++m) {
    ah[m] = *reinterpret_cast<const half8*>(&Ah[wr * 64 + m * 16 + rr][kb]);
    al[m] = *reinterpret_cast<const half8*>(&Al[wr * 64 + m * 16 + rr][kb]);
  }
#pragma unroll
  for (int n = 0; n < 4; ++n) {
    const half8 bh = *reinterpret_cast<const half8*>(&Bh[wc * 64 + n * 16 + rr][kb]);
    const half8 bl = *reinterpret_cast<const half8*>(&Bl[wc * 64 + n * 16 + rr][kb]);
#pragma unroll
    for (int m = 0; m < 4; ++m) {
      acc[m][n] = __builtin_amdgcn_mfma_f32_16x16x32_f16(ah[m], bh, acc[m][n], 0, 0, 0);
      acc[m][n] = __builtin_amdgcn_mfma_f32_16x16x32_f16(al[m], bh, acc[m][n], 0, 0, 0);
      acc[m][n] = __builtin_amdgcn_mfma_f32_16x16x32_f16(ah[m], bl, acc[m][n], 0, 0, 0);
    }
  }
}

// A plain x B plain (1 term), both [40] T-layout.
__device__ __forceinline__ void mma128_plain(const _Float16 (*Ah)[40], const _Float16 (*Bh)[40],
                                             float4v acc[4][4], int lane, int wr, int wc) {
  const int g = lane >> 4, rr = lane & 15, kb = g << 3;
  half8 ah[4];
#pragma unroll
  for (int m = 0; m < 4; ++m)
    ah[m] = *reinterpret_cast<const half8*>(&Ah[wr * 64 + m * 16 + rr][kb]);
#pragma unroll
  for (int n = 0; n < 4; ++n) {
    const half8 b = *reinterpret_cast<const half8*>(&Bh[wc * 64 + n * 16 + rr][kb]);
#pragma unroll
    for (int m = 0; m < 4; ++m)
      acc[m][n] = __builtin_amdgcn_mfma_f32_16x16x32_f16(ah[m], b, acc[m][n], 0, 0, 0);
  }
}

// A plain [40] x B-transposed [44] (g4).
__device__ __forceinline__ void mma128_bt(const _Float16 (*Ah)[40], const _Float16 (*Bt)[44],
                                          float4v acc[4][4], int lane, int wr, int wc) {
  const int g = lane >> 4, rr = lane & 15, kb = g << 3;
  half8 ah[4];
#pragma unroll
  for (int m = 0; m < 4; ++m)
    ah[m] = *reinterpret_cast<const half8*>(&Ah[wr * 64 + m * 16 + rr][kb]);
#pragma unroll
  for (int n = 0; n < 4; ++n) {
    const half8 b = *reinterpret_cast<const half8*>(&Bt[wc * 64 + n * 16 + rr][kb]);
#pragma unroll
    for (int m = 0; m < 4; ++m)
      acc[m][n] = __builtin_amdgcn_mfma_f32_16x16x32_f16(ah[m], b, acc[m][n], 0, 0, 0);
  }
}

// ---------------------------------------------------------------------------
// G1: q = source @ W_in^T. NEW: 128x128 tile, split3, 512 blocks.
// Swizzle: XCD x owns w in [x*64,(x+1)*64) -> Win fully L2-resident per XCD.
// ---------------------------------------------------------------------------
__global__ void __launch_bounds__(256) g1_k(const float* __restrict__ src,
                                            const float* __restrict__ Win,
                                            _Float16* __restrict__ qh,
                                            _Float16* __restrict__ ql) {
  __shared__ _Float16 Ah[128][40], Al[128][40], Bh[128][40], Bl[128][40];
  const int tid = threadIdx.x, lane = tid & 63, wv = tid >> 6;
  const int wr = wv >> 1, wc = wv & 1;
  const int f = blockIdx.y * 8 + blockIdx.x;       // 0..511
  const int w = (f & 7) * 64 + (f >> 3);           // XCD-contiguous remap
  const int row0 = (w >> 3) * 128, col0 = (w & 7) * 128;
  float4v acc[4][4] = {};
  for (int k0 = 0; k0 < Dn; k0 += 32) {
    stageT_split(src, Dn, row0, k0, Ah, Al, tid);
    stageT_split(Win, Dn, col0, k0, Bh, Bl, tid);
    __syncthreads();
    mma128_split3(Ah, Al, Bh, Bl, acc, lane, wr, wc);
    __syncthreads();
  }
  const int g = lane >> 4, rr = lane & 15;
#pragma unroll
  for (int m = 0; m < 4; ++m)
#pragma unroll
    for (int n = 0; n < 4; ++n)
#pragma unroll
      for (int i = 0; i < 4; ++i) {
        const int row = row0 + wr * 64 + m * 16 + g * 4 + i;
        const int col = col0 + wc * 64 + n * 16 + rr;
        _Float16 h, l; split2(acc[m][n][i], h, l);
        qh[(size_t)row * Dn + col] = h;
        ql[(size_t)row * Dn + col] = l;
      }
}

// ---------------------------------------------------------------------------
// G2: align[b] = q[b] @ mb[b]^T -> out1 [T][B][S]. 128x128 split3.
// 512 blocks; 8 batches/XCD. (unchanged from round 8)
// ---------------------------------------------------------------------------
__global__ void __launch_bounds__(256) g2_k(const _Float16* __restrict__ qh,
                                            const _Float16* __restrict__ ql,
                                            const float* __restrict__ mb,
                                            float* __restrict__ out1) {
  __shared__ _Float16 Ah[128][40], Al[128][40], Bh[128][40], Bl[128][40];
  const int tid = threadIdx.x, lane = tid & 63, wv = tid >> 6;
  const int wr = wv >> 1, wc = wv & 1;
  const int id = blockIdx.z * 8 + blockIdx.x;      // 0..511
  const int j = id >> 3;
  const int b = (id & 7) * 8 + (j >> 3), col0 = (j & 7) * 128;
  const _Float16* qhb = qh + (size_t)b * Tn * Dn;
  const _Float16* qlb = ql + (size_t)b * Tn * Dn;
  const float* mbb = mb + (size_t)b * Sn * Dn;
  float* Cb = out1 + (size_t)b * Sn;
  float4v acc[4][4] = {};
  for (int k0 = 0; k0 < Dn; k0 += 32) {
    stageT_h16(qhb, qlb, Dn, 0, k0, Ah, Al, tid);
    stageT_split(mbb, Dn, col0, k0, Bh, Bl, tid);
    __syncthreads();
    mma128_split3(Ah, Al, Bh, Bl, acc, lane, wr, wc);
    __syncthreads();
  }
  const int g = lane >> 4, rr = lane & 15;
#pragma unroll
  for (int m = 0; m < 4; ++m)
#pragma unroll
    for (int n = 0; n < 4; ++n)
#pragma unroll
      for (int i = 0; i < 4; ++i) {
        const int t = wr * 64 + m * 16 + g * 4 + i;
        const int s = col0 + wc * 64 + n * 16 + rr;
        Cb[(size_t)t * (Bn * Sn) + s] = acc[m][n][i];
      }
}

// ---------------------------------------------------------------------------
// Softmax + probs rescale + renorm; av -> out1 (f32) AND avh (fp16 for g4).
// ---------------------------------------------------------------------------
__device__ __forceinline__ float block_max(float v, float* red, int tid) {
#pragma unroll
  for (int o = 32; o; o >>= 1) v = fmaxf(v, __shfl_xor(v, o));
  if ((tid & 63) == 0) red[tid >> 6] = v;
  __syncthreads();
  v = fmaxf(fmaxf(red[0], red[1]), fmaxf(red[2], red[3]));
  __syncthreads();
  return v;
}

__device__ __forceinline__ float block_sum(float v, float* red, int tid) {
#pragma unroll
  for (int o = 32; o; o >>= 1) v += __shfl_xor(v, o);
  if ((tid & 63) == 0) red[tid >> 6] = v;
  __syncthreads();
  v = red[0] + red[1] + red[2] + red[3];
  __syncthreads();
  return v;
}

__global__ void __launch_bounds__(256) softmax_k(float* __restrict__ av_io,
                                                 const float* __restrict__ probs,
                                                 const int* __restrict__ lens,
                                                 float* __restrict__ out_nore,
                                                 _Float16* __restrict__ avh) {
  __shared__ float red[4];
  const int r = blockIdx.x;        // t*B + b
  const int b = r & (Bn - 1);
  const int tid = threadIdx.x;
  const int len = lens[b];
  float* row = av_io + (size_t)r * Sn;
  const int s0 = tid * 4;

  const float4 x = *reinterpret_cast<const float4*>(row + s0);
  const bool v0 = (s0 + 0) < len, v1 = (s0 + 1) < len, v2 = (s0 + 2) < len, v3 = (s0 + 3) < len;

  float lm = -1e30f;
  if (v0) lm = fmaxf(lm, x.x);
  if (v1) lm = fmaxf(lm, x.y);
  if (v2) lm = fmaxf(lm, x.z);
  if (v3) lm = fmaxf(lm, x.w);
  const float m = block_max(lm, red, tid);

  const float e0 = v0 ? __expf(x.x - m) : 0.f;
  const float e1 = v1 ? __expf(x.y - m) : 0.f;
  const float e2 = v2 ? __expf(x.z - m) : 0.f;
  const float e3 = v3 ? __expf(x.w - m) : 0.f;
  const float esum = block_sum(e0 + e1 + e2 + e3, red, tid);
  const float rs = 1.f / esum;
  const float n0 = e0 * rs, n1 = e1 * rs, n2 = e2 * rs, n3 = e3 * rs;
  *reinterpret_cast<float4*>(out_nore + (size_t)r * Sn + s0) = make_float4(n0, n1, n2, n3);

  const float4 p = *reinterpret_cast<const float4*>(probs + (size_t)b * Sn + s0);
  const float c0 = n0 * p.x, c1 = n1 * p.y, c2 = n2 * p.z, c3 = n3 * p.w;
  const float ssum = block_sum(c0 + c1 + c2 + c3, red, tid);
  const float rss = 1.f / ssum;
  const float a0 = c0 * rss, a1 = c1 * rss, a2 = c2 * rss, a3 = c3 * rss;
  *reinterpret_cast<float4*>(row + s0) = make_float4(a0, a1, a2, a3);
  half4 hv = {(_Float16)a0, (_Float16)a1, (_Float16)a2, (_Float16)a3};
  *reinterpret_cast<half4*>(avh + (size_t)r * Sn + s0) = hv;
}

// ---------------------------------------------------------------------------
// G4: c[b] = av[b] @ mb[b]. A = av16 copy, B = mb write-transposed.
// 512 blocks; 8 batches/XCD. c written fp16. (unchanged from round 8)
// ---------------------------------------------------------------------------
__global__ void __launch_bounds__(256) g4_k(const _Float16* __restrict__ avh,
                                            const float* __restrict__ mb,
                                            _Float16* __restrict__ c) {
  __shared__ _Float16 Ah[128][40];
  __shared__ _Float16 Bt[128][44];
  const int tid = threadIdx.x, lane = tid & 63, wv = tid >> 6;
  const int wr = wv >> 1, wc = wv & 1;
  const int id = blockIdx.z * 8 + blockIdx.x;
  const int j = id >> 3;
  const int b = (id & 7) * 8 + (j >> 3), col0 = (j & 7) * 128;
  const _Float16* avb = avh + (size_t)b * Sn;       // row stride Bn*Sn
  const float* mbb = mb + (size_t)b * Sn * Dn;
  _Float16* cb = c + (size_t)b * Tn * Dn;
  float4v acc[4][4] = {};
  for (int k0 = 0; k0 < Sn; k0 += 32) {
    stage128x32_h16(avb, (size_t)Bn * Sn, 0, k0, Ah, tid);
    stageB_trans(mbb, Dn, k0, col0, Bt, tid);
    __syncthreads();
    mma128_bt(Ah, Bt, acc, lane, wr, wc);
    __syncthreads();
  }
  const int g = lane >> 4, rr = lane & 15;
#pragma unroll
  for (int m = 0; m < 4; ++m)
#pragma unroll
    for (int n = 0; n < 4; ++n)
#pragma unroll
      for (int i = 0; i < 4; ++i) {
        const int t = wr * 64 + m * 16 + g * 4 + i;
        const int d = col0 + wc * 64 + n * 16 + rr;
        cb[(size_t)t * Dn + d] = (_Float16)acc[m][n][i];
      }
}

// ---------------------------------------------------------------------------
// G5: attn_h = tanh([c, src] @ W_out^T) -> out0 [T][B][D].
// NEW: 128x128 tile, BK=32, plain, 512 blocks (halves Wout refetch).
// A: k<1024 pure fp16 copy from c; k>=1024 cvt from src. B: cvt from Wout.
// ---------------------------------------------------------------------------
__global__ void __launch_bounds__(256) g5_k(const _Float16* __restrict__ c,
                                            const float* __restrict__ src,
                                            const float* __restrict__ Wout,
                                            float* __restrict__ out0) {
  __shared__ _Float16 Ah[128][40], Bh[128][40];
  const int tid = threadIdx.x, lane = tid & 63, wv = tid >> 6;
  const int wr = wv >> 1, wc = wv & 1;
  const int f = blockIdx.y * 8 + blockIdx.x;       // 0..511
  const int w = (f & 7) * 64 + (f >> 3);           // XCD-contiguous remap
  const int row0 = (w >> 3) * 128, col0 = (w & 7) * 128;
  float4v acc[4][4] = {};
  for (int k0 = 0; k0 < 2 * Dn; k0 += 32) {
    if (k0 < Dn) stage128x32_h16(c, Dn, row0, k0, Ah, tid);
    else         stageT_plain(src, Dn, row0, k0 - Dn, Ah, tid);
    stageT_plain(Wout, 2 * Dn, col0, k0, Bh, tid);
    __syncthreads();
    mma128_plain(Ah, Bh, acc, lane, wr, wc);
    __syncthreads();
  }
  const int g = lane >> 4, rr = lane & 15;
  const int bb = row0 >> 7;                        // single batch per block
#pragma unroll
  for (int m = 0; m < 4; ++m)
#pragma unroll
    for (int n = 0; n < 4; ++n)
#pragma unroll
      for (int i = 0; i < 4; ++i) {
        const int mm = row0 + wr * 64 + m * 16 + g * 4 + i;
        const int t = mm & 127;          // % T
        const int d = col0 + wc * 64 + n * 16 + rr;
        out0[((size_t)t * Bn + bb) * Dn + d] = tanhf(acc[m][n][i]);
      }
}

// ---------------------------------------------------------------------------

extern "C" void kernel_launch(void* const* d_in, const int* in_sizes, int n_in,
                              void* d_out, int out_size, void* d_ws, size_t ws_size,
                              hipStream_t stream) {
  const float* src   = (const float*)d_in[0];   // [B,T,D]
  const float* mb    = (const float*)d_in[1];   // [B,S,D]
  const float* probs = (const float*)d_in[2];   // [B,S]
  const int*   lens  = (const int*)d_in[3];     // [B]
  const float* Win   = (const float*)d_in[4];   // [D,D]
  const float* Wout  = (const float*)d_in[5];   // [D,2D]

  float* out  = (float*)d_out;
  float* out0 = out;                              // attn_h      [T,B,D]
  float* out1 = out + (size_t)Tn * Bn * Dn;       // align_vec   [T,B,S]
  float* out2 = out1 + (size_t)Tn * Bn * Sn;      // norescale   [T,B,S]

  // ws layout: [qh 16.8M][ql 16.8M][avh 16.8M]; cbuf overwrites qh/ql after g2.
  _Float16* qh  = (_Float16*)d_ws;
  _Float16* ql  = qh + (size_t)Bn * Tn * Dn;
  _Float16* avh = ql + (size_t)Bn * Tn * Dn;      // [t*B+b][S] fp16 av
  _Float16* cbuf = (_Float16*)d_ws;               // reuses q region after g2

  // 1) q = source @ W_in^T (split fp16 output)  (128x128 tile)
  g1_k<<<dim3(8, 64), 256, 0, stream>>>(src, Win, qh, ql);

  // 2) align[b] = q[b] @ mb[b]^T -> out1 [T][B][S]  (128x128 tile)
  g2_k<<<dim3(8, 1, Bn), 256, 0, stream>>>(qh, ql, mb, out1);

  // 3) masked softmax + rescale + renormalize (also emits av fp16)
  softmax_k<<<Tn * Bn, 256, 0, stream>>>(out1, probs, lens, out2, avh);

  // 4) c[b] = av[b] @ mb[b] -> fp16 (overwrites q region in ws)
  g4_k<<<dim3(Dn / 128, 1, Bn), 256, 0, stream>>>(avh, mb, cbuf);

  // 5) attn_h = tanh([c, src] @ W_out^T) -> out0 [T][B][D]  (128x128 tile)
  g5_k<<<dim3(8, 64), 256, 0, stream>>>(cbuf, src, Wout, out0);
}

// Round 10
// 301.471 us; speedup vs baseline: 1.1306x; 1.1306x over previous
//
#include <hip/hip_runtime.h>
#include <cmath>

constexpr int Bn = 64;    // batch
constexpr int Tn = 128;   // tgt len
constexpr int Sn = 1024;  // src len
constexpr int Dn = 1024;  // model dim

typedef __attribute__((ext_vector_type(8))) _Float16 half8;
typedef __attribute__((ext_vector_type(4))) _Float16 half4;
typedef __attribute__((ext_vector_type(4))) float float4v;

__device__ __forceinline__ void split2(float x, _Float16& h, _Float16& l) {
  h = (_Float16)x;
  l = (_Float16)(x - (float)h);
}

// ---------------------------------------------------------------------------
// LDS staging (ds_writes only; ordered by __syncthreads).
// [rows][BK] k-contiguous; row stride 40 halves (80 B) for BK=32, 72 halves
// for BK=64 — 8-row bank periods (<=2-way conflict, free).
// ---------------------------------------------------------------------------

// 128-row f32 source -> split hi/lo, BK=32.
__device__ __forceinline__ void stageT_split(const float* __restrict__ G, size_t ld,
                                             int row0, int k0,
                                             _Float16 (*Sh)[40], _Float16 (*Sl)[40],
                                             int tid) {
#pragma unroll
  for (int it = 0; it < 4; ++it) {
    const int f = tid + it * 256;
    const int r = f >> 3, kq = (f & 7) << 2;
    const float4 v = *reinterpret_cast<const float4*>(G + (size_t)(row0 + r) * ld + k0 + kq);
    _Float16 h0, h1, h2, h3, l0, l1, l2, l3;
    split2(v.x, h0, l0); split2(v.y, h1, l1); split2(v.z, h2, l2); split2(v.w, h3, l3);
    half4 hv = {h0, h1, h2, h3};
    half4 lv = {l0, l1, l2, l3};
    *reinterpret_cast<half4*>(&Sh[r][kq]) = hv;
    *reinterpret_cast<half4*>(&Sl[r][kq]) = lv;
  }
}

// 64-row f32 source -> split hi/lo, BK=32.
__device__ __forceinline__ void stageT_split64(const float* __restrict__ G, size_t ld,
                                               int row0, int k0,
                                               _Float16 (*Sh)[40], _Float16 (*Sl)[40],
                                               int tid) {
#pragma unroll
  for (int it = 0; it < 2; ++it) {
    const int f = tid + it * 256;
    const int r = f >> 3, kq = (f & 7) << 2;
    const float4 v = *reinterpret_cast<const float4*>(G + (size_t)(row0 + r) * ld + k0 + kq);
    _Float16 h0, h1, h2, h3, l0, l1, l2, l3;
    split2(v.x, h0, l0); split2(v.y, h1, l1); split2(v.z, h2, l2); split2(v.w, h3, l3);
    half4 hv = {h0, h1, h2, h3};
    half4 lv = {l0, l1, l2, l3};
    *reinterpret_cast<half4*>(&Sh[r][kq]) = hv;
    *reinterpret_cast<half4*>(&Sl[r][kq]) = lv;
  }
}

// Pre-split fp16 source (q) -> copy, 128 rows, BK=32.
__device__ __forceinline__ void stageT_h16(const _Float16* __restrict__ Gh,
                                           const _Float16* __restrict__ Gl, size_t ld,
                                           int row0, int k0,
                                           _Float16 (*Sh)[40], _Float16 (*Sl)[40],
                                           int tid) {
#pragma unroll
  for (int it = 0; it < 2; ++it) {
    const int f = tid + it * 256;
    const int r = f >> 2, kq = (f & 3) << 3;
    *reinterpret_cast<half8*>(&Sh[r][kq]) =
        *reinterpret_cast<const half8*>(Gh + (size_t)(row0 + r) * ld + k0 + kq);
    *reinterpret_cast<half8*>(&Sl[r][kq]) =
        *reinterpret_cast<const half8*>(Gl + (size_t)(row0 + r) * ld + k0 + kq);
  }
}

// fp16 source, 128 rows x 32 k single tile: pure copy (g4 A = av16).
__device__ __forceinline__ void stage128x32_h16(const _Float16* __restrict__ G, size_t ld,
                                                int k0, _Float16 (*Sh)[40], int tid) {
#pragma unroll
  for (int it = 0; it < 2; ++it) {
    const int f = tid + it * 256;
    const int r = f >> 2, kq = (f & 3) << 3;
    *reinterpret_cast<half8*>(&Sh[r][kq]) =
        *reinterpret_cast<const half8*>(G + (size_t)r * ld + k0 + kq);
  }
}

// g4 B: mb tile [32 k][128 d] f32 -> WRITE-TRANSPOSED fp16 [128 d][44 k].
__device__ __forceinline__ void stageB_trans(const float* __restrict__ G, size_t ld,
                                             int k0, int col0,
                                             _Float16 (*Bt)[44], int tid) {
  const int d = tid & 127;
  const int kb = (tid >> 7) * 4;       // 0 or 4
#pragma unroll
  for (int it = 0; it < 4; ++it) {
    const int kq = kb + it * 8;        // covers 0..31
    _Float16 h[4];
#pragma unroll
    for (int j = 0; j < 4; ++j)
      h[j] = (_Float16)G[(size_t)(k0 + kq + j) * ld + col0 + d];
    half4 hv = {h[0], h[1], h[2], h[3]};
    *reinterpret_cast<half4*>(&Bt[d][kq]) = hv;
  }
}

// g5 BK=64 helpers ----------------------------------------------------------

__device__ __forceinline__ void stage64x64_h16(const _Float16* __restrict__ G, size_t ld,
                                               int row0, int k0,
                                               _Float16 (*Sh)[72], int tid) {
#pragma unroll
  for (int it = 0; it < 2; ++it) {
    const int f = tid + it * 256;
    const int r = f >> 3, kq = (f & 7) << 3;
    *reinterpret_cast<half8*>(&Sh[r][kq]) =
        *reinterpret_cast<const half8*>(G + (size_t)(row0 + r) * ld + k0 + kq);
  }
}

__device__ __forceinline__ void stage64x64_f32(const float* __restrict__ G, size_t ld,
                                               int row0, int k0,
                                               _Float16 (*Sh)[72], int tid) {
#pragma unroll
  for (int it = 0; it < 4; ++it) {
    const int f = tid + it * 256;
    const int r = f >> 4, kq = (f & 15) << 2;
    const float4 v = *reinterpret_cast<const float4*>(G + (size_t)(row0 + r) * ld + k0 + kq);
    half4 hv = {(_Float16)v.x, (_Float16)v.y, (_Float16)v.z, (_Float16)v.w};
    *reinterpret_cast<half4*>(&Sh[r][kq]) = hv;
  }
}

__device__ __forceinline__ void stage128x64_f32(const float* __restrict__ G, size_t ld,
                                                int row0, int k0,
                                                _Float16 (*Sh)[72], int tid) {
#pragma unroll
  for (int it = 0; it < 8; ++it) {
    const int f = tid + it * 256;
    const int r = f >> 4, kq = (f & 15) << 2;
    const float4 v = *reinterpret_cast<const float4*>(G + (size_t)(row0 + r) * ld + k0 + kq);
    half4 hv = {(_Float16)v.x, (_Float16)v.y, (_Float16)v.z, (_Float16)v.w};
    *reinterpret_cast<half4*>(&Sh[r][kq]) = hv;
  }
}

// ---------------------------------------------------------------------------
// MFMA cores, 16x16x32. Input frag: row/col = lane&15, k = 8*(lane>>4)+[0..7].
// C/D: col = lane&15, row = (lane>>4)*4 + i  [m89-verified].
// ---------------------------------------------------------------------------

// g1: 64x128 tile, 4 waves 1x4, A split x B split (3 terms).
__device__ __forceinline__ void mma64_split3(const _Float16 (*Ah)[40], const _Float16 (*Al)[40],
                                             const _Float16 (*Bh)[40], const _Float16 (*Bl)[40],
                                             float4v acc[4][2], int lane, int wc) {
  const int g = lane >> 4, rr = lane & 15, kb = g << 3;
  half8 ah[4], al[4];
#pragma unroll
  for (int m = 0; m < 4; ++m) {
    ah[m] = *reinterpret_cast<const half8*>(&Ah[m * 16 + rr][kb]);
    al[m] = *reinterpret_cast<const half8*>(&Al[m * 16 + rr][kb]);
  }
#pragma unroll
  for (int n = 0; n < 2; ++n) {
    const half8 bh = *reinterpret_cast<const half8*>(&Bh[wc * 32 + n * 16 + rr][kb]);
    const half8 bl = *reinterpret_cast<const half8*>(&Bl[wc * 32 + n * 16 + rr][kb]);
#pragma unroll
    for (int m = 0; m < 4; ++m) {
      acc[m][n] = __builtin_amdgcn_mfma_f32_16x16x32_f16(ah[m], bh, acc[m][n], 0, 0, 0);
      acc[m][n] = __builtin_amdgcn_mfma_f32_16x16x32_f16(al[m], bh, acc[m][n], 0, 0, 0);
      acc[m][n] = __builtin_amdgcn_mfma_f32_16x16x32_f16(ah[m], bl, acc[m][n], 0, 0, 0);
    }
  }
}

// g2: 128x128 tile, 4 waves 2x2, A split x B split (3 terms), acc[4][4].
__device__ __forceinline__ void mma128_split3(const _Float16 (*Ah)[40], const _Float16 (*Al)[40],
                                              const _Float16 (*Bh)[40], const _Float16 (*Bl)[40],
                                              float4v acc[4][4], int lane, int wr, int wc) {
  const int g = lane >> 4, rr = lane & 15, kb = g << 3;
  half8 ah[4], al[4];
#pragma unroll
  for (int m = 0; m < 4; ++m) {
    ah[m] = *reinterpret_cast<const half8*>(&Ah[wr * 64 + m * 16 + rr][kb]);
    al[m] = *reinterpret_cast<const half8*>(&Al[wr * 64 + m * 16 + rr][kb]);
  }
#pragma unroll
  for (int n = 0; n < 4; ++n) {
    const half8 bh = *reinterpret_cast<const half8*>(&Bh[wc * 64 + n * 16 + rr][kb]);
    const half8 bl = *reinterpret_cast<const half8*>(&Bl[wc * 64 + n * 16 + rr][kb]);
#pragma unroll
    for (int m = 0; m < 4; ++m) {
      acc[m][n] = __builtin_amdgcn_mfma_f32_16x16x32_f16(ah[m], bh, acc[m][n], 0, 0, 0);
      acc[m][n] = __builtin_amdgcn_mfma_f32_16x16x32_f16(al[m], bh, acc[m][n], 0, 0, 0);
      acc[m][n] = __builtin_amdgcn_mfma_f32_16x16x32_f16(ah[m], bl, acc[m][n], 0, 0, 0);
    }
  }
}

// g4: 128x128 tile, 4 waves 2x2, A[40] x B-transposed[44], plain (1 term).
__device__ __forceinline__ void mma128_bt(const _Float16 (*Ah)[40], const _Float16 (*Bt)[44],
                                          float4v acc[4][4], int lane, int wr, int wc) {
  const int g = lane >> 4, rr = lane & 15, kb = g << 3;
  half8 ah[4];
#pragma unroll
  for (int m = 0; m < 4; ++m)
    ah[m] = *reinterpret_cast<const half8*>(&Ah[wr * 64 + m * 16 + rr][kb]);
#pragma unroll
  for (int n = 0; n < 4; ++n) {
    const half8 b = *reinterpret_cast<const half8*>(&Bt[wc * 64 + n * 16 + rr][kb]);
#pragma unroll
    for (int m = 0; m < 4; ++m)
      acc[m][n] = __builtin_amdgcn_mfma_f32_16x16x32_f16(ah[m], b, acc[m][n], 0, 0, 0);
  }
}

// g5: 64x128 tile, BK=64, 4 waves 1x4, plain (1 term).
__device__ __forceinline__ void mma64_bk64_plain(const _Float16 (*Ah)[72], const _Float16 (*Bh)[72],
                                                 float4v acc[4][2], int lane, int wc) {
  const int g = lane >> 4, rr = lane & 15;
#pragma unroll
  for (int kk = 0; kk < 2; ++kk) {
    const int kb = kk * 32 + (g << 3);
    half8 ah[4];
#pragma unroll
    for (int m = 0; m < 4; ++m)
      ah[m] = *reinterpret_cast<const half8*>(&Ah[m * 16 + rr][kb]);
#pragma unroll
    for (int n = 0; n < 2; ++n) {
      const half8 b = *reinterpret_cast<const half8*>(&Bh[wc * 32 + n * 16 + rr][kb]);
#pragma unroll
      for (int m = 0; m < 4; ++m)
        acc[m][n] = __builtin_amdgcn_mfma_f32_16x16x32_f16(ah[m], b, acc[m][n], 0, 0, 0);
    }
  }
}

// ---------------------------------------------------------------------------
// G1: q = source @ W_in^T. BM=64, BN=128, split3, 1024 blocks. (round-8 cfg)
// ---------------------------------------------------------------------------
__global__ void __launch_bounds__(256) g1_k(const float* __restrict__ src,
                                            const float* __restrict__ Win,
                                            _Float16* __restrict__ qh,
                                            _Float16* __restrict__ ql) {
  __shared__ _Float16 Ah[64][40], Al[64][40], Bh[128][40], Bl[128][40];
  const int tid = threadIdx.x, lane = tid & 63, wc = tid >> 6;
  const int f = blockIdx.y * 8 + blockIdx.x;
  const int w = (f & 7) * 128 + (f >> 3);          // XCD-contiguous remap
  const int row0 = (w >> 3) * 64, col0 = (w & 7) * 128;
  float4v acc[4][2] = {};
  for (int k0 = 0; k0 < Dn; k0 += 32) {
    stageT_split64(src, Dn, row0, k0, Ah, Al, tid);
    stageT_split(Win, Dn, col0, k0, Bh, Bl, tid);
    __syncthreads();
    mma64_split3(Ah, Al, Bh, Bl, acc, lane, wc);
    __syncthreads();
  }
  const int g = lane >> 4, rr = lane & 15;
#pragma unroll
  for (int m = 0; m < 4; ++m)
#pragma unroll
    for (int n = 0; n < 2; ++n)
#pragma unroll
      for (int i = 0; i < 4; ++i) {
        const int row = row0 + m * 16 + g * 4 + i;
        const int col = col0 + wc * 32 + n * 16 + rr;
        _Float16 h, l; split2(acc[m][n][i], h, l);
        qh[(size_t)row * Dn + col] = h;
        ql[(size_t)row * Dn + col] = l;
      }
}

// ---------------------------------------------------------------------------
// G2: align[b] = q[b] @ mb[b]^T -> out1 [T][B][S]. 128x128 split3.
// NEW: blocks with col0 >= len[b] exit immediately — their outputs are fully
// overwritten with exact zeros by softmax_k (masked region), never consumed.
// ---------------------------------------------------------------------------
__global__ void __launch_bounds__(256) g2_k(const _Float16* __restrict__ qh,
                                            const _Float16* __restrict__ ql,
                                            const float* __restrict__ mb,
                                            const int* __restrict__ lens,
                                            float* __restrict__ out1) {
  __shared__ _Float16 Ah[128][40], Al[128][40], Bh[128][40], Bl[128][40];
  const int tid = threadIdx.x, lane = tid & 63, wv = tid >> 6;
  const int wr = wv >> 1, wc = wv & 1;
  const int id = blockIdx.z * 8 + blockIdx.x;      // 0..511
  const int j = id >> 3;
  const int b = (id & 7) * 8 + (j >> 3), col0 = (j & 7) * 128;
  if (col0 >= lens[b]) return;                     // masked column-block: dead output
  const _Float16* qhb = qh + (size_t)b * Tn * Dn;
  const _Float16* qlb = ql + (size_t)b * Tn * Dn;
  const float* mbb = mb + (size_t)b * Sn * Dn;
  float* Cb = out1 + (size_t)b * Sn;
  float4v acc[4][4] = {};
  for (int k0 = 0; k0 < Dn; k0 += 32) {
    stageT_h16(qhb, qlb, Dn, 0, k0, Ah, Al, tid);
    stageT_split(mbb, Dn, col0, k0, Bh, Bl, tid);
    __syncthreads();
    mma128_split3(Ah, Al, Bh, Bl, acc, lane, wr, wc);
    __syncthreads();
  }
  const int g = lane >> 4, rr = lane & 15;
#pragma unroll
  for (int m = 0; m < 4; ++m)
#pragma unroll
    for (int n = 0; n < 4; ++n)
#pragma unroll
      for (int i = 0; i < 4; ++i) {
        const int t = wr * 64 + m * 16 + g * 4 + i;
        const int s = col0 + wc * 64 + n * 16 + rr;
        Cb[(size_t)t * (Bn * Sn) + s] = acc[m][n][i];
      }
}

// ---------------------------------------------------------------------------
// Softmax + probs rescale + renorm; av -> out1 (f32) AND avh (fp16 for g4).
// Writes exact zeros at masked positions (covers g2's skipped blocks).
// ---------------------------------------------------------------------------
__device__ __forceinline__ float block_max(float v, float* red, int tid) {
#pragma unroll
  for (int o = 32; o; o >>= 1) v = fmaxf(v, __shfl_xor(v, o));
  if ((tid & 63) == 0) red[tid >> 6] = v;
  __syncthreads();
  v = fmaxf(fmaxf(red[0], red[1]), fmaxf(red[2], red[3]));
  __syncthreads();
  return v;
}

__device__ __forceinline__ float block_sum(float v, float* red, int tid) {
#pragma unroll
  for (int o = 32; o; o >>= 1) v += __shfl_xor(v, o);
  if ((tid & 63) == 0) red[tid >> 6] = v;
  __syncthreads();
  v = red[0] + red[1] + red[2] + red[3];
  __syncthreads();
  return v;
}

__global__ void __launch_bounds__(256) softmax_k(float* __restrict__ av_io,
                                                 const float* __restrict__ probs,
                                                 const int* __restrict__ lens,
                                                 float* __restrict__ out_nore,
                                                 _Float16* __restrict__ avh) {
  __shared__ float red[4];
  const int r = blockIdx.x;        // t*B + b
  const int b = r & (Bn - 1);
  const int tid = threadIdx.x;
  const int len = lens[b];
  float* row = av_io + (size_t)r * Sn;
  const int s0 = tid * 4;

  const float4 x = *reinterpret_cast<const float4*>(row + s0);
  const bool v0 = (s0 + 0) < len, v1 = (s0 + 1) < len, v2 = (s0 + 2) < len, v3 = (s0 + 3) < len;

  float lm = -1e30f;
  if (v0) lm = fmaxf(lm, x.x);
  if (v1) lm = fmaxf(lm, x.y);
  if (v2) lm = fmaxf(lm, x.z);
  if (v3) lm = fmaxf(lm, x.w);
  const float m = block_max(lm, red, tid);

  const float e0 = v0 ? __expf(x.x - m) : 0.f;
  const float e1 = v1 ? __expf(x.y - m) : 0.f;
  const float e2 = v2 ? __expf(x.z - m) : 0.f;
  const float e3 = v3 ? __expf(x.w - m) : 0.f;
  const float esum = block_sum(e0 + e1 + e2 + e3, red, tid);
  const float rs = 1.f / esum;
  const float n0 = e0 * rs, n1 = e1 * rs, n2 = e2 * rs, n3 = e3 * rs;
  *reinterpret_cast<float4*>(out_nore + (size_t)r * Sn + s0) = make_float4(n0, n1, n2, n3);

  const float4 p = *reinterpret_cast<const float4*>(probs + (size_t)b * Sn + s0);
  const float c0 = n0 * p.x, c1 = n1 * p.y, c2 = n2 * p.z, c3 = n3 * p.w;
  const float ssum = block_sum(c0 + c1 + c2 + c3, red, tid);
  const float rss = 1.f / ssum;
  const float a0 = c0 * rss, a1 = c1 * rss, a2 = c2 * rss, a3 = c3 * rss;
  *reinterpret_cast<float4*>(row + s0) = make_float4(a0, a1, a2, a3);
  half4 hv = {(_Float16)a0, (_Float16)a1, (_Float16)a2, (_Float16)a3};
  *reinterpret_cast<half4*>(avh + (size_t)r * Sn + s0) = hv;
}

// ---------------------------------------------------------------------------
// G4: c[b] = av[b] @ mb[b]. A = av16 copy, B = mb write-transposed.
// NEW: K-loop truncated at roundup(len[b],32) — av rows are exactly 0 beyond
// len, so skipped products contribute exactly 0.
// ---------------------------------------------------------------------------
__global__ void __launch_bounds__(256) g4_k(const _Float16* __restrict__ avh,
                                            const float* __restrict__ mb,
                                            const int* __restrict__ lens,
                                            _Float16* __restrict__ c) {
  __shared__ _Float16 Ah[128][40];
  __shared__ _Float16 Bt[128][44];
  const int tid = threadIdx.x, lane = tid & 63, wv = tid >> 6;
  const int wr = wv >> 1, wc = wv & 1;
  const int id = blockIdx.z * 8 + blockIdx.x;
  const int j = id >> 3;
  const int b = (id & 7) * 8 + (j >> 3), col0 = (j & 7) * 128;
  const int kmax = (lens[b] + 31) & ~31;            // uniform per block
  const _Float16* avb = avh + (size_t)b * Sn;       // row stride Bn*Sn
  const float* mbb = mb + (size_t)b * Sn * Dn;
  _Float16* cb = c + (size_t)b * Tn * Dn;
  float4v acc[4][4] = {};
  for (int k0 = 0; k0 < kmax; k0 += 32) {
    stage128x32_h16(avb, (size_t)Bn * Sn, k0, Ah, tid);
    stageB_trans(mbb, Dn, k0, col0, Bt, tid);
    __syncthreads();
    mma128_bt(Ah, Bt, acc, lane, wr, wc);
    __syncthreads();
  }
  const int g = lane >> 4, rr = lane & 15;
#pragma unroll
  for (int m = 0; m < 4; ++m)
#pragma unroll
    for (int n = 0; n < 4; ++n)
#pragma unroll
      for (int i = 0; i < 4; ++i) {
        const int t = wr * 64 + m * 16 + g * 4 + i;
        const int d = col0 + wc * 64 + n * 16 + rr;
        cb[(size_t)t * Dn + d] = (_Float16)acc[m][n][i];
      }
}

// ---------------------------------------------------------------------------
// G5: attn_h = tanh([c, src] @ W_out^T) -> out0 [T][B][D].
// BM=64, BN=128, BK=64, plain (round-8 cfg).
// ---------------------------------------------------------------------------
__global__ void __launch_bounds__(256) g5_k(const _Float16* __restrict__ c,
                                            const float* __restrict__ src,
                                            const float* __restrict__ Wout,
                                            float* __restrict__ out0) {
  __shared__ _Float16 Ah[64][72], Bh[128][72];
  const int tid = threadIdx.x, lane = tid & 63, wc = tid >> 6;
  const int f = blockIdx.y * 8 + blockIdx.x;
  const int w = (f & 7) * 128 + (f >> 3);
  const int row0 = (w >> 3) * 64, col0 = (w & 7) * 128;
  float4v acc[4][2] = {};
  for (int k0 = 0; k0 < 2 * Dn; k0 += 64) {
    if (k0 < Dn) stage64x64_h16(c, Dn, row0, k0, Ah, tid);
    else         stage64x64_f32(src, Dn, row0, k0 - Dn, Ah, tid);
    stage128x64_f32(Wout, 2 * Dn, col0, k0, Bh, tid);
    __syncthreads();
    mma64_bk64_plain(Ah, Bh, acc, lane, wc);
    __syncthreads();
  }
  const int g = lane >> 4, rr = lane & 15;
#pragma unroll
  for (int m = 0; m < 4; ++m)
#pragma unroll
    for (int n = 0; n < 2; ++n)
#pragma unroll
      for (int i = 0; i < 4; ++i) {
        const int mm = row0 + m * 16 + g * 4 + i;
        const int bb = mm >> 7;          // / T
        const int t = mm & 127;          // % T
        const int d = col0 + wc * 32 + n * 16 + rr;
        out0[((size_t)t * Bn + bb) * Dn + d] = tanhf(acc[m][n][i]);
      }
}

// ---------------------------------------------------------------------------

extern "C" void kernel_launch(void* const* d_in, const int* in_sizes, int n_in,
                              void* d_out, int out_size, void* d_ws, size_t ws_size,
                              hipStream_t stream) {
  const float* src   = (const float*)d_in[0];   // [B,T,D]
  const float* mb    = (const float*)d_in[1];   // [B,S,D]
  const float* probs = (const float*)d_in[2];   // [B,S]
  const int*   lens  = (const int*)d_in[3];     // [B]
  const float* Win   = (const float*)d_in[4];   // [D,D]
  const float* Wout  = (const float*)d_in[5];   // [D,2D]

  float* out  = (float*)d_out;
  float* out0 = out;                              // attn_h      [T,B,D]
  float* out1 = out + (size_t)Tn * Bn * Dn;       // align_vec   [T,B,S]
  float* out2 = out1 + (size_t)Tn * Bn * Sn;      // norescale   [T,B,S]

  // ws layout: [qh 16.8M][ql 16.8M][avh 16.8M]; cbuf overwrites qh/ql after g2.
  _Float16* qh  = (_Float16*)d_ws;
  _Float16* ql  = qh + (size_t)Bn * Tn * Dn;
  _Float16* avh = ql + (size_t)Bn * Tn * Dn;      // [t*B+b][S] fp16 av
  _Float16* cbuf = (_Float16*)d_ws;               // reuses q region after g2

  // 1) q = source @ W_in^T (split fp16 output)
  g1_k<<<dim3(Dn / 128, (Bn * Tn) / 64), 256, 0, stream>>>(src, Win, qh, ql);

  // 2) align[b] = q[b] @ mb[b]^T -> out1 [T][B][S]  (128x128, mask-skip)
  g2_k<<<dim3(8, 1, Bn), 256, 0, stream>>>(qh, ql, mb, lens, out1);

  // 3) masked softmax + rescale + renormalize (also emits av fp16)
  softmax_k<<<Tn * Bn, 256, 0, stream>>>(out1, probs, lens, out2, avh);

  // 4) c[b] = av[b] @ mb[b] -> fp16 (K truncated at len[b])
  g4_k<<<dim3(Dn / 128, 1, Bn), 256, 0, stream>>>(avh, mb, lens, cbuf);

  // 5) attn_h = tanh([c, src] @ W_out^T) -> out0 [T][B][D]
  g5_k<<<dim3(Dn / 128, (Bn * Tn) / 64), 256, 0, stream>>>(cbuf, src, Wout, out0);
}